// Round 21
// baseline (184.540 us; speedup 1.0000x reference)
//
#include <hip/hip_runtime.h>

#define D 128

typedef __bf16 v8bf __attribute__((ext_vector_type(8)));
typedef float v4f __attribute__((ext_vector_type(4)));

__device__ __forceinline__ unsigned short f2bfbits(float f) {
    unsigned u = __float_as_uint(f);
    u += 0x7FFFu + ((u >> 16) & 1u);
    return (unsigned short)(u >> 16);
}

__device__ __forceinline__ float4 ldbf4(const __bf16* p) {
    const uint2 u = *reinterpret_cast<const uint2*>(p);
    float4 r;
    r.x = __uint_as_float(u.x << 16);
    r.y = __uint_as_float(u.x & 0xFFFF0000u);
    r.z = __uint_as_float(u.y << 16);
    r.w = __uint_as_float(u.y & 0xFFFF0000u);
    return r;
}

// ====== K0 (fat): blocks [0,128) = W -> bf16 col-major preswizzle;
//   blocks [128,...) = zero bnsums + scanctr + deg (replaces hipMemset). ======
__global__ __launch_bounds__(256) void wprep_zero_k(
    const float* __restrict__ Wl, const float* __restrict__ Wr,
    __bf16* __restrict__ Wbf, int* __restrict__ zbase, int zcount) {
    if ((int)blockIdx.x < 128) {
        const int i = blockIdx.x * 256 + threadIdx.x;  // 0..32767
        const int cg = i >> 7;
        const int k = i & 127;
        const float* __restrict__ Wp = (cg < D) ? Wl : Wr;
        Wbf[i] = (__bf16)Wp[(size_t)k * D + (cg & (D - 1))];
        return;
    }
    const int i = ((int)blockIdx.x - 128) * 256 + threadIdx.x;
    if (i < zcount) zbase[i] = 0;
}

// ====== K2 (fat): blocks [0,gemmGrid) = persistent MFMA GEMM (swapped
//   operands -> packed 8B C-stores; LDS-staged, reg-prefetch pipeline);
//   blocks [gemmGrid,...) = deg histogram + per-edge rank capture. ======
__global__ __launch_bounds__(256, 1) void gemm_deg_k(
    const float* __restrict__ x, const __bf16* __restrict__ Wbf,
    __bf16* __restrict__ xl, __bf16* __restrict__ xr, int n, int nTiles,
    int gemmGrid, const int* __restrict__ dst, int* __restrict__ deg,
    unsigned char* __restrict__ rank, int E) {
    if ((int)blockIdx.x >= gemmGrid) {
        const int e = ((int)blockIdx.x - gemmGrid) * 256 + threadIdx.x;
        if (e < E) rank[e] = (unsigned char)atomicAdd(&deg[dst[e]], 1);
        return;
    }
    __shared__ __align__(16) unsigned short xs[64][136];  // +8 pad
    const int tid = threadIdx.x;
    const int lane = tid & 63;
    const int wid = tid >> 6;
    const int col16 = lane & 15;
    const int kg = lane >> 4;

    // W fragments: loaded ONCE per block (L2-hot, 64 KB shared by all)
    v8bf bfr[4][4];
#pragma unroll
    for (int nt = 0; nt < 4; ++nt) {
        const int cg = (wid * 4 + nt) * 16 + col16;
#pragma unroll
        for (int ks = 0; ks < 4; ++ks)
            bfr[nt][ks] = *reinterpret_cast<const v8bf*>(
                &Wbf[(size_t)cg * 128 + ks * 32 + kg * 8]);
    }

    v8bf pre[4];
    int tile = (int)blockIdx.x;
    {
        const int row0 = tile * 64;
#pragma unroll
        for (int j = 0; j < 4; ++j) {
            const int i = tid + j * 256;
            const int row = row0 + (i >> 4);
            const int k0 = (i & 15) * 8;
            float4 v0 = make_float4(0.f, 0.f, 0.f, 0.f), v1 = v0;
            if (row < n) {
                v0 = *reinterpret_cast<const float4*>(&x[(size_t)row * D + k0]);
                v1 = *reinterpret_cast<const float4*>(&x[(size_t)row * D + k0 + 4]);
            }
            v8bf t;
            t[0] = (__bf16)v0.x; t[1] = (__bf16)v0.y;
            t[2] = (__bf16)v0.z; t[3] = (__bf16)v0.w;
            t[4] = (__bf16)v1.x; t[5] = (__bf16)v1.y;
            t[6] = (__bf16)v1.z; t[7] = (__bf16)v1.w;
            pre[j] = t;
        }
    }

    while (tile < nTiles) {
        const int row0 = tile * 64;
#pragma unroll
        for (int j = 0; j < 4; ++j) {
            const int i = tid + j * 256;
            *reinterpret_cast<v8bf*>(&xs[i >> 4][(i & 15) * 8]) = pre[j];
        }
        __syncthreads();

        const int next = tile + gemmGrid;
        if (next < nTiles) {
            const int nrow0 = next * 64;
#pragma unroll
            for (int j = 0; j < 4; ++j) {
                const int i = tid + j * 256;
                const int row = nrow0 + (i >> 4);
                const int k0 = (i & 15) * 8;
                float4 v0 = make_float4(0.f, 0.f, 0.f, 0.f), v1 = v0;
                if (row < n) {
                    v0 = *reinterpret_cast<const float4*>(&x[(size_t)row * D + k0]);
                    v1 = *reinterpret_cast<const float4*>(&x[(size_t)row * D + k0 + 4]);
                }
                v8bf t;
                t[0] = (__bf16)v0.x; t[1] = (__bf16)v0.y;
                t[2] = (__bf16)v0.z; t[3] = (__bf16)v0.w;
                t[4] = (__bf16)v1.x; t[5] = (__bf16)v1.y;
                t[6] = (__bf16)v1.z; t[7] = (__bf16)v1.w;
                pre[j] = t;
            }
        }

        // swapped operands: acc[mt][nt][r] = C[row0+mt*16+col16,
        //                                     (wid*4+nt)*16 + kg*4 + r]
        v4f acc[4][4] = {};
#pragma unroll
        for (int mt = 0; mt < 4; ++mt) {
            v8bf afr[4];
#pragma unroll
            for (int ks = 0; ks < 4; ++ks)
                afr[ks] = *reinterpret_cast<const v8bf*>(
                    &xs[mt * 16 + col16][ks * 32 + kg * 8]);
#pragma unroll
            for (int nt = 0; nt < 4; ++nt)
#pragma unroll
                for (int ks = 0; ks < 4; ++ks)
                    acc[mt][nt] = __builtin_amdgcn_mfma_f32_16x16x32_bf16(
                        bfr[nt][ks], afr[ks], acc[mt][nt], 0, 0, 0);
        }
#pragma unroll
        for (int mt = 0; mt < 4; ++mt) {
            const int row = row0 + mt * 16 + col16;
            if (row < n) {
#pragma unroll
                for (int nt = 0; nt < 4; ++nt) {
                    const int cgb = (wid * 4 + nt) * 16 + kg * 4;
                    __bf16* __restrict__ op = (cgb < D) ? xl : xr;
                    const int c = cgb & (D - 1);
                    uint2 pkt;
                    pkt.x = ((unsigned)f2bfbits(acc[mt][nt][1]) << 16) |
                            f2bfbits(acc[mt][nt][0]);
                    pkt.y = ((unsigned)f2bfbits(acc[mt][nt][3]) << 16) |
                            f2bfbits(acc[mt][nt][2]);
                    *reinterpret_cast<uint2*>(&op[(size_t)row * D + c]) = pkt;
                }
            }
        }
        __syncthreads();
        tile = next;
    }
}

// ====== single-pass ticket scan: per-chunk LDS scan + atomic chunk base. ======
__global__ __launch_bounds__(256) void scan_k(
    const int* __restrict__ deg, int* __restrict__ rowptr,
    int* __restrict__ scanctr, int n) {
    __shared__ int tmp[256];
    __shared__ int sbase;
    const int i = blockIdx.x * 256 + threadIdx.x;
    const int v = (i < n) ? deg[i] : 0;
    tmp[threadIdx.x] = v;
    __syncthreads();
    for (int off = 1; off < 256; off <<= 1) {
        int t = (threadIdx.x >= off) ? tmp[threadIdx.x - off] : 0;
        __syncthreads();
        tmp[threadIdx.x] += t;
        __syncthreads();
    }
    if (threadIdx.x == 255) sbase = atomicAdd(scanctr, tmp[255]);
    __syncthreads();
    if (i < n) rowptr[i] = sbase + tmp[threadIdx.x] - v;
}

// ====== fill: ATOMIC-FREE scatter via rowptr[d] + rank[e].
// XCD-partitioned so each epay line is written by one XCD's L2. ======
__global__ __launch_bounds__(256) void fill_k(
    const int* __restrict__ src, const int* __restrict__ dst,
    const float* __restrict__ ew, const int* __restrict__ rowptr,
    const unsigned char* __restrict__ rank, int2* __restrict__ epay,
    int E, int n) {
    const int xcd = blockIdx.x & 7;
    const int nchunk = gridDim.x >> 3;
    const int slice = (n + 7) >> 3;
    const int lo = xcd * slice;
    const int hi = min(n, lo + slice);
    const int stride = nchunk * 256;
    for (int e = ((int)blockIdx.x >> 3) * 256 + threadIdx.x; e < E; e += stride) {
        const int d = dst[e];
        if (d >= lo && d < hi) {
            const int p = rowptr[d] + (int)rank[e];
            int2 v;
            v.x = src[e];
            v.y = __float_as_int(ew[e]);
            epay[p] = v;
        }
    }
}

// ====== node_aggr: fused logits + plain-exp softmax + aggregation.
// One pair of nodes per wave; 8-edge unroll -> 8 independent xl gathers
// in flight per wave (L2/L3-miss latency hiding; VGPR ~70, still headroom). ======
__global__ __launch_bounds__(256) void node_aggr_k(
    const __bf16* __restrict__ xl, const __bf16* __restrict__ xr,
    const int2* __restrict__ epay, const int* __restrict__ rowptr,
    const int* __restrict__ deg, const float* __restrict__ We,
    const float* __restrict__ att, __bf16* __restrict__ outb, int n) {
    const int wgl = (int)((blockIdx.x * (size_t)blockDim.x + threadIdx.x) >> 6);
    const int lane = threadIdx.x & 63;
    const int half = lane >> 5;
    const int node = wgl * 2 + half;
    const int ch = (lane & 31) * 4;

    int beg = 0, dg = 0;
    if (node < n) {
        beg = rowptr[node];
        dg = deg[node];
    }
    const int end = beg + dg;
    const int tmax = max(dg, __shfl_xor(dg, 32));

    float4 b = make_float4(0.f, 0.f, 0.f, 0.f);
    if (node < n) b = ldbf4(&xr[(size_t)node * D + ch]);
    const float4 we4 = *reinterpret_cast<const float4*>(&We[ch]);
    const float4 at4 = *reinterpret_cast<const float4*>(&att[ch]);

    float s = 0.f;
    float4 acc = make_float4(0.f, 0.f, 0.f, 0.f);
    for (int t = 0; t < tmax; t += 8) {
        float part[8];
        float4 av[8];
#pragma unroll
        for (int i = 0; i < 8; ++i) {
            const int p = beg + t + i;
            const int q = max(min(p, end - 1), 0);
            const int2 pw = epay[q];
            av[i] = ldbf4(&xl[(size_t)pw.x * D + ch]);
            const float wgt = __int_as_float(pw.y);
            float c0 = fmaf(wgt, we4.x, av[i].x + b.x);
            float c1 = fmaf(wgt, we4.y, av[i].y + b.y);
            float c2 = fmaf(wgt, we4.z, av[i].z + b.z);
            float c3 = fmaf(wgt, we4.w, av[i].w + b.w);
            c0 = fmaxf(c0, 0.2f * c0);
            c1 = fmaxf(c1, 0.2f * c1);
            c2 = fmaxf(c2, 0.2f * c2);
            c3 = fmaxf(c3, 0.2f * c3);
            part[i] = fmaf(c3, at4.w, fmaf(c2, at4.z, fmaf(c1, at4.y, c0 * at4.x)));
        }
#pragma unroll
        for (int off = 1; off < 8; off <<= 1) {
#pragma unroll
            for (int i = 0; i < 8; ++i) part[i] += __shfl_xor(part[i], off);
        }
        float pv[8];
#pragma unroll
        for (int i = 0; i < 8; ++i)
            pv[i] = (t + i < dg) ? __expf(fminf(part[i], 50.f)) : 0.f;
        s += ((pv[0] + pv[1]) + (pv[2] + pv[3])) +
             ((pv[4] + pv[5]) + (pv[6] + pv[7]));
        float4 a0, a1;
        a0.x = fmaf(pv[3], av[3].x, fmaf(pv[2], av[2].x,
               fmaf(pv[1], av[1].x, pv[0] * av[0].x)));
        a0.y = fmaf(pv[3], av[3].y, fmaf(pv[2], av[2].y,
               fmaf(pv[1], av[1].y, pv[0] * av[0].y)));
        a0.z = fmaf(pv[3], av[3].z, fmaf(pv[2], av[2].z,
               fmaf(pv[1], av[1].z, pv[0] * av[0].z)));
        a0.w = fmaf(pv[3], av[3].w, fmaf(pv[2], av[2].w,
               fmaf(pv[1], av[1].w, pv[0] * av[0].w)));
        a1.x = fmaf(pv[7], av[7].x, fmaf(pv[6], av[6].x,
               fmaf(pv[5], av[5].x, pv[4] * av[4].x)));
        a1.y = fmaf(pv[7], av[7].y, fmaf(pv[6], av[6].y,
               fmaf(pv[5], av[5].y, pv[4] * av[4].y)));
        a1.z = fmaf(pv[7], av[7].z, fmaf(pv[6], av[6].z,
               fmaf(pv[5], av[5].z, pv[4] * av[4].z)));
        a1.w = fmaf(pv[7], av[7].w, fmaf(pv[6], av[6].w,
               fmaf(pv[5], av[5].w, pv[4] * av[4].w)));
        acc.x += a0.x + a1.x;
        acc.y += a0.y + a1.y;
        acc.z += a0.z + a1.z;
        acc.w += a0.w + a1.w;
    }
    if (node < n) {
        const float inv = 1.f / (s + 1e-16f);
        uint2 pkt;
        pkt.x = ((unsigned)f2bfbits(acc.y * inv) << 16) | f2bfbits(acc.x * inv);
        pkt.y = ((unsigned)f2bfbits(acc.w * inv) << 16) | f2bfbits(acc.z * inv);
        *reinterpret_cast<uint2*>(&outb[(size_t)node * D + ch]) = pkt;
    }
}

// ============ BN partial sums over bf16 intermediate ============
__global__ __launch_bounds__(256) void bn_partial_k(
    const __bf16* __restrict__ outb, float* __restrict__ sums,
    float* __restrict__ sumsq, int n) {
    __shared__ float rs[8][128];
    __shared__ float rq[8][128];
    const int c4 = (threadIdx.x & 31) * 4;
    const int rstr = threadIdx.x >> 5;  // 0..7
    float4 s = make_float4(0.f, 0.f, 0.f, 0.f);
    float4 q = make_float4(0.f, 0.f, 0.f, 0.f);
    for (int r = blockIdx.x * 8 + rstr; r < n; r += gridDim.x * 8) {
        const float4 v = ldbf4(&outb[(size_t)r * D + c4]);
        s.x += v.x; s.y += v.y; s.z += v.z; s.w += v.w;
        q.x = fmaf(v.x, v.x, q.x);
        q.y = fmaf(v.y, v.y, q.y);
        q.z = fmaf(v.z, v.z, q.z);
        q.w = fmaf(v.w, v.w, q.w);
    }
    rs[rstr][c4 + 0] = s.x; rs[rstr][c4 + 1] = s.y;
    rs[rstr][c4 + 2] = s.z; rs[rstr][c4 + 3] = s.w;
    rq[rstr][c4 + 0] = q.x; rq[rstr][c4 + 1] = q.y;
    rq[rstr][c4 + 2] = q.z; rq[rstr][c4 + 3] = q.w;
    __syncthreads();
    const int t = threadIdx.x;
    if (t < 128) {
        float a = 0.f;
#pragma unroll
        for (int j = 0; j < 8; ++j) a += rs[j][t];
        atomicAdd(&sums[t], a);
    } else {
        const int c = t - 128;
        float a = 0.f;
#pragma unroll
        for (int j = 0; j < 8; ++j) a += rq[j][c];
        atomicAdd(&sumsq[c], a);
    }
}

// ============ BN finalize+apply: bf16 in, f32 out ============
__global__ __launch_bounds__(256) void bn_apply_k(
    const __bf16* __restrict__ outb, float* __restrict__ out,
    const float* __restrict__ bnsums, const float* __restrict__ gamma,
    const float* __restrict__ beta, int n, int total4) {
    const int i = blockIdx.x * blockDim.x + threadIdx.x;
    if (i >= total4) return;
    const int c4 = (i & 31) * 4;
    const float inv_n = 1.f / (float)n;
    const float4 sm = *reinterpret_cast<const float4*>(&bnsums[c4]);
    const float4 sq = *reinterpret_cast<const float4*>(&bnsums[D + c4]);
    const float4 g = *reinterpret_cast<const float4*>(&gamma[c4]);
    const float4 bt = *reinterpret_cast<const float4*>(&beta[c4]);
    float4 v = ldbf4(&outb[(size_t)i * 4]);
    float mu, var, scale, shift, r;
    mu = sm.x * inv_n; var = fmaxf(sq.x * inv_n - mu * mu, 0.f);
    scale = g.x * rsqrtf(var + 1e-5f); shift = bt.x - mu * scale;
    r = fmaf(v.x, scale, shift); v.x = fmaxf(r, 0.01f * r);
    mu = sm.y * inv_n; var = fmaxf(sq.y * inv_n - mu * mu, 0.f);
    scale = g.y * rsqrtf(var + 1e-5f); shift = bt.y - mu * scale;
    r = fmaf(v.y, scale, shift); v.y = fmaxf(r, 0.01f * r);
    mu = sm.z * inv_n; var = fmaxf(sq.z * inv_n - mu * mu, 0.f);
    scale = g.z * rsqrtf(var + 1e-5f); shift = bt.z - mu * scale;
    r = fmaf(v.z, scale, shift); v.z = fmaxf(r, 0.01f * r);
    mu = sm.w * inv_n; var = fmaxf(sq.w * inv_n - mu * mu, 0.f);
    scale = g.w * rsqrtf(var + 1e-5f); shift = bt.w - mu * scale;
    r = fmaf(v.w, scale, shift); v.w = fmaxf(r, 0.01f * r);
    *reinterpret_cast<float4*>(&out[(size_t)i * 4]) = v;
}

extern "C" void kernel_launch(void* const* d_in, const int* in_sizes, int n_in,
                              void* d_out, int out_size, void* d_ws, size_t ws_size,
                              hipStream_t stream) {
    const float* x     = (const float*)d_in[0];
    const int*   ei    = (const int*)d_in[1];
    const float* ew    = (const float*)d_in[2];
    const float* Wl    = (const float*)d_in[3];
    const float* Wr    = (const float*)d_in[4];
    const float* We    = (const float*)d_in[5];
    const float* att   = (const float*)d_in[6];
    // d_in[7] = bias: cancels exactly inside BatchNorm (mean subtraction)
    const float* gamma = (const float*)d_in[8];
    const float* beta  = (const float*)d_in[9];

    const int n = in_sizes[0] / D;   // 100000 nodes
    const int E = in_sizes[2];       // 800000 edges
    const int* src = ei;
    const int* dst = ei + E;
    const int nblk = (n + 255) / 256;

    char* ws = (char*)d_ws;
    size_t off = 0;
    __bf16* xl = (__bf16*)(ws + off);   off += (size_t)n * D * 2;
    __bf16* xr = (__bf16*)(ws + off);   off += (size_t)n * D * 2;
    __bf16* outb = (__bf16*)(ws + off); off += (size_t)n * D * 2;
    __bf16* Wbf = (__bf16*)(ws + off);  off += (size_t)2 * D * D * 2;
    // zero region (contiguous): bnsums (2*D f) + scanctr (4) + deg (n ints)
    float* bnsums = (float*)(ws + off); off += 2 * D * sizeof(float);
    int* scanctr = (int*)(ws + off);    off += 4 * sizeof(int);
    int* deg = (int*)(ws + off);        off += (size_t)n * sizeof(int);
    int* rowptr = (int*)(ws + off);     off += ((size_t)n + 1) * sizeof(int);
    unsigned char* rank = (unsigned char*)(ws + off); off += (size_t)E;
    off = (off + 15) & ~(size_t)15;
    int2* epay = (int2*)(ws + off);     off += (size_t)E * sizeof(int2);

    float* outacc = (float*)d_out;

    const int zcount = 2 * D + 4 + n;
    const int zblocks = (zcount + 255) / 256;

    // K0: W preswizzle || zero deg/bnsums/scanctr
    wprep_zero_k<<<128 + zblocks, 256, 0, stream>>>(Wl, Wr, Wbf,
                                                    (int*)bnsums, zcount);

    // persistent MFMA GEMM (512 blocks) || deg + rank capture
    const int nTiles = (n + 63) / 64;
    const int gemmGrid = 512;
    const int degBlocks = (E + 255) / 256;
    gemm_deg_k<<<gemmGrid + degBlocks, 256, 0, stream>>>(
        x, Wbf, xl, xr, n, nTiles, gemmGrid, dst, deg, rank, E);

    // single-pass ticket scan
    scan_k<<<nblk, 256, 0, stream>>>(deg, rowptr, scanctr, n);

    // atomic-free XCD-partitioned payload scatter
    fill_k<<<2048, 256, 0, stream>>>(src, dst, ew, rowptr, rank, epay, E, n);

    // one pair of nodes per wave, 8-edge unroll
    const int waves = (n + 1) / 2;
    node_aggr_k<<<(waves + 3) / 4, 256, 0, stream>>>(xl, xr, epay, rowptr,
                                                     deg, We, att, outb, n);

    bn_partial_k<<<512, 256, 0, stream>>>(outb, bnsums, bnsums + D, n);
    bn_apply_k<<<((n * D / 4) + 255) / 256, 256, 0, stream>>>(
        outb, outacc, bnsums, gamma, beta, n, n * D / 4);
}

// Round 22
// 170.952 us; speedup vs baseline: 1.0795x; 1.0795x over previous
//
#include <hip/hip_runtime.h>

#define D 128

typedef __bf16 v8bf __attribute__((ext_vector_type(8)));
typedef float v4f __attribute__((ext_vector_type(4)));

__device__ __forceinline__ unsigned short f2bfbits(float f) {
    unsigned u = __float_as_uint(f);
    u += 0x7FFFu + ((u >> 16) & 1u);
    return (unsigned short)(u >> 16);
}

__device__ __forceinline__ float4 ldbf4(const __bf16* p) {
    const uint2 u = *reinterpret_cast<const uint2*>(p);
    float4 r;
    r.x = __uint_as_float(u.x << 16);
    r.y = __uint_as_float(u.x & 0xFFFF0000u);
    r.z = __uint_as_float(u.y << 16);
    r.w = __uint_as_float(u.y & 0xFFFF0000u);
    return r;
}

// ====== K0 (fat): blocks [0,128) = W -> bf16 col-major preswizzle;
//   blocks [128,...) = zero bnsums + scanctr + deg (replaces hipMemset). ======
__global__ __launch_bounds__(256) void wprep_zero_k(
    const float* __restrict__ Wl, const float* __restrict__ Wr,
    __bf16* __restrict__ Wbf, int* __restrict__ zbase, int zcount) {
    if ((int)blockIdx.x < 128) {
        const int i = blockIdx.x * 256 + threadIdx.x;  // 0..32767
        const int cg = i >> 7;
        const int k = i & 127;
        const float* __restrict__ Wp = (cg < D) ? Wl : Wr;
        Wbf[i] = (__bf16)Wp[(size_t)k * D + (cg & (D - 1))];
        return;
    }
    const int i = ((int)blockIdx.x - 128) * 256 + threadIdx.x;
    if (i < zcount) zbase[i] = 0;
}

// ====== K2 (fat): blocks [0,gemmGrid) = persistent MFMA GEMM (swapped
//   operands -> packed 8B C-stores; LDS-staged, reg-prefetch pipeline);
//   blocks [gemmGrid,...) = deg histogram + per-edge rank capture. ======
__global__ __launch_bounds__(256, 1) void gemm_deg_k(
    const float* __restrict__ x, const __bf16* __restrict__ Wbf,
    __bf16* __restrict__ xl, __bf16* __restrict__ xr, int n, int nTiles,
    int gemmGrid, const int* __restrict__ dst, int* __restrict__ deg,
    unsigned char* __restrict__ rank, int E) {
    if ((int)blockIdx.x >= gemmGrid) {
        const int e = ((int)blockIdx.x - gemmGrid) * 256 + threadIdx.x;
        if (e < E) rank[e] = (unsigned char)atomicAdd(&deg[dst[e]], 1);
        return;
    }
    __shared__ __align__(16) unsigned short xs[64][136];  // +8 pad
    const int tid = threadIdx.x;
    const int lane = tid & 63;
    const int wid = tid >> 6;
    const int col16 = lane & 15;
    const int kg = lane >> 4;

    // W fragments: loaded ONCE per block (L2-hot, 64 KB shared by all)
    v8bf bfr[4][4];
#pragma unroll
    for (int nt = 0; nt < 4; ++nt) {
        const int cg = (wid * 4 + nt) * 16 + col16;
#pragma unroll
        for (int ks = 0; ks < 4; ++ks)
            bfr[nt][ks] = *reinterpret_cast<const v8bf*>(
                &Wbf[(size_t)cg * 128 + ks * 32 + kg * 8]);
    }

    v8bf pre[4];
    int tile = (int)blockIdx.x;
    {
        const int row0 = tile * 64;
#pragma unroll
        for (int j = 0; j < 4; ++j) {
            const int i = tid + j * 256;
            const int row = row0 + (i >> 4);
            const int k0 = (i & 15) * 8;
            float4 v0 = make_float4(0.f, 0.f, 0.f, 0.f), v1 = v0;
            if (row < n) {
                v0 = *reinterpret_cast<const float4*>(&x[(size_t)row * D + k0]);
                v1 = *reinterpret_cast<const float4*>(&x[(size_t)row * D + k0 + 4]);
            }
            v8bf t;
            t[0] = (__bf16)v0.x; t[1] = (__bf16)v0.y;
            t[2] = (__bf16)v0.z; t[3] = (__bf16)v0.w;
            t[4] = (__bf16)v1.x; t[5] = (__bf16)v1.y;
            t[6] = (__bf16)v1.z; t[7] = (__bf16)v1.w;
            pre[j] = t;
        }
    }

    while (tile < nTiles) {
        const int row0 = tile * 64;
#pragma unroll
        for (int j = 0; j < 4; ++j) {
            const int i = tid + j * 256;
            *reinterpret_cast<v8bf*>(&xs[i >> 4][(i & 15) * 8]) = pre[j];
        }
        __syncthreads();

        const int next = tile + gemmGrid;
        if (next < nTiles) {
            const int nrow0 = next * 64;
#pragma unroll
            for (int j = 0; j < 4; ++j) {
                const int i = tid + j * 256;
                const int row = nrow0 + (i >> 4);
                const int k0 = (i & 15) * 8;
                float4 v0 = make_float4(0.f, 0.f, 0.f, 0.f), v1 = v0;
                if (row < n) {
                    v0 = *reinterpret_cast<const float4*>(&x[(size_t)row * D + k0]);
                    v1 = *reinterpret_cast<const float4*>(&x[(size_t)row * D + k0 + 4]);
                }
                v8bf t;
                t[0] = (__bf16)v0.x; t[1] = (__bf16)v0.y;
                t[2] = (__bf16)v0.z; t[3] = (__bf16)v0.w;
                t[4] = (__bf16)v1.x; t[5] = (__bf16)v1.y;
                t[6] = (__bf16)v1.z; t[7] = (__bf16)v1.w;
                pre[j] = t;
            }
        }

        // swapped operands: acc[mt][nt][r] = C[row0+mt*16+col16,
        //                                     (wid*4+nt)*16 + kg*4 + r]
        v4f acc[4][4] = {};
#pragma unroll
        for (int mt = 0; mt < 4; ++mt) {
            v8bf afr[4];
#pragma unroll
            for (int ks = 0; ks < 4; ++ks)
                afr[ks] = *reinterpret_cast<const v8bf*>(
                    &xs[mt * 16 + col16][ks * 32 + kg * 8]);
#pragma unroll
            for (int nt = 0; nt < 4; ++nt)
#pragma unroll
                for (int ks = 0; ks < 4; ++ks)
                    acc[mt][nt] = __builtin_amdgcn_mfma_f32_16x16x32_bf16(
                        bfr[nt][ks], afr[ks], acc[mt][nt], 0, 0, 0);
        }
#pragma unroll
        for (int mt = 0; mt < 4; ++mt) {
            const int row = row0 + mt * 16 + col16;
            if (row < n) {
#pragma unroll
                for (int nt = 0; nt < 4; ++nt) {
                    const int cgb = (wid * 4 + nt) * 16 + kg * 4;
                    __bf16* __restrict__ op = (cgb < D) ? xl : xr;
                    const int c = cgb & (D - 1);
                    uint2 pkt;
                    pkt.x = ((unsigned)f2bfbits(acc[mt][nt][1]) << 16) |
                            f2bfbits(acc[mt][nt][0]);
                    pkt.y = ((unsigned)f2bfbits(acc[mt][nt][3]) << 16) |
                            f2bfbits(acc[mt][nt][2]);
                    *reinterpret_cast<uint2*>(&op[(size_t)row * D + c]) = pkt;
                }
            }
        }
        __syncthreads();
        tile = next;
    }
}

// ====== single-pass ticket scan: per-chunk LDS scan + atomic chunk base. ======
__global__ __launch_bounds__(256) void scan_k(
    const int* __restrict__ deg, int* __restrict__ rowptr,
    int* __restrict__ scanctr, int n) {
    __shared__ int tmp[256];
    __shared__ int sbase;
    const int i = blockIdx.x * 256 + threadIdx.x;
    const int v = (i < n) ? deg[i] : 0;
    tmp[threadIdx.x] = v;
    __syncthreads();
    for (int off = 1; off < 256; off <<= 1) {
        int t = (threadIdx.x >= off) ? tmp[threadIdx.x - off] : 0;
        __syncthreads();
        tmp[threadIdx.x] += t;
        __syncthreads();
    }
    if (threadIdx.x == 255) sbase = atomicAdd(scanctr, tmp[255]);
    __syncthreads();
    if (i < n) rowptr[i] = sbase + tmp[threadIdx.x] - v;
}

// ====== fill: ATOMIC-FREE scatter via rowptr[d] + rank[e].
// XCD-partitioned so each epay line is written by one XCD's L2. ======
__global__ __launch_bounds__(256) void fill_k(
    const int* __restrict__ src, const int* __restrict__ dst,
    const float* __restrict__ ew, const int* __restrict__ rowptr,
    const unsigned char* __restrict__ rank, int2* __restrict__ epay,
    int E, int n) {
    const int xcd = blockIdx.x & 7;
    const int nchunk = gridDim.x >> 3;
    const int slice = (n + 7) >> 3;
    const int lo = xcd * slice;
    const int hi = min(n, lo + slice);
    const int stride = nchunk * 256;
    for (int e = ((int)blockIdx.x >> 3) * 256 + threadIdx.x; e < E; e += stride) {
        const int d = dst[e];
        if (d >= lo && d < hi) {
            const int p = rowptr[d] + (int)rank[e];
            int2 v;
            v.x = src[e];
            v.y = __float_as_int(ew[e]);
            epay[p] = v;
        }
    }
}

// ====== node_aggr: fused logits + plain-exp softmax + aggregation.
// One pair of nodes per wave; 4-edge unroll (best-measured MLP/occupancy). ======
__global__ __launch_bounds__(256) void node_aggr_k(
    const __bf16* __restrict__ xl, const __bf16* __restrict__ xr,
    const int2* __restrict__ epay, const int* __restrict__ rowptr,
    const int* __restrict__ deg, const float* __restrict__ We,
    const float* __restrict__ att, __bf16* __restrict__ outb, int n) {
    const int wgl = (int)((blockIdx.x * (size_t)blockDim.x + threadIdx.x) >> 6);
    const int lane = threadIdx.x & 63;
    const int half = lane >> 5;
    const int node = wgl * 2 + half;
    const int ch = (lane & 31) * 4;

    int beg = 0, dg = 0;
    if (node < n) {
        beg = rowptr[node];
        dg = deg[node];
    }
    const int end = beg + dg;
    const int tmax = max(dg, __shfl_xor(dg, 32));

    float4 b = make_float4(0.f, 0.f, 0.f, 0.f);
    if (node < n) b = ldbf4(&xr[(size_t)node * D + ch]);
    const float4 we4 = *reinterpret_cast<const float4*>(&We[ch]);
    const float4 at4 = *reinterpret_cast<const float4*>(&att[ch]);

    float s = 0.f;
    float4 acc = make_float4(0.f, 0.f, 0.f, 0.f);
    for (int t = 0; t < tmax; t += 4) {
        float part[4];
        float4 av[4];
#pragma unroll
        for (int i = 0; i < 4; ++i) {
            const int p = beg + t + i;
            const int q = max(min(p, end - 1), 0);
            const int2 pw = epay[q];
            av[i] = ldbf4(&xl[(size_t)pw.x * D + ch]);
            const float wgt = __int_as_float(pw.y);
            float c0 = fmaf(wgt, we4.x, av[i].x + b.x);
            float c1 = fmaf(wgt, we4.y, av[i].y + b.y);
            float c2 = fmaf(wgt, we4.z, av[i].z + b.z);
            float c3 = fmaf(wgt, we4.w, av[i].w + b.w);
            c0 = fmaxf(c0, 0.2f * c0);
            c1 = fmaxf(c1, 0.2f * c1);
            c2 = fmaxf(c2, 0.2f * c2);
            c3 = fmaxf(c3, 0.2f * c3);
            part[i] = fmaf(c3, at4.w, fmaf(c2, at4.z, fmaf(c1, at4.y, c0 * at4.x)));
        }
#pragma unroll
        for (int off = 1; off < 8; off <<= 1) {
            part[0] += __shfl_xor(part[0], off);
            part[1] += __shfl_xor(part[1], off);
            part[2] += __shfl_xor(part[2], off);
            part[3] += __shfl_xor(part[3], off);
        }
        const float pv0 = (t + 0 < dg) ? __expf(fminf(part[0], 50.f)) : 0.f;
        const float pv1 = (t + 1 < dg) ? __expf(fminf(part[1], 50.f)) : 0.f;
        const float pv2 = (t + 2 < dg) ? __expf(fminf(part[2], 50.f)) : 0.f;
        const float pv3 = (t + 3 < dg) ? __expf(fminf(part[3], 50.f)) : 0.f;
        s += (pv0 + pv1) + (pv2 + pv3);
        acc.x += fmaf(pv3, av[3].x, fmaf(pv2, av[2].x,
                 fmaf(pv1, av[1].x, pv0 * av[0].x)));
        acc.y += fmaf(pv3, av[3].y, fmaf(pv2, av[2].y,
                 fmaf(pv1, av[1].y, pv0 * av[0].y)));
        acc.z += fmaf(pv3, av[3].z, fmaf(pv2, av[2].z,
                 fmaf(pv1, av[1].z, pv0 * av[0].z)));
        acc.w += fmaf(pv3, av[3].w, fmaf(pv2, av[2].w,
                 fmaf(pv1, av[1].w, pv0 * av[0].w)));
    }
    if (node < n) {
        const float inv = 1.f / (s + 1e-16f);
        uint2 pkt;
        pkt.x = ((unsigned)f2bfbits(acc.y * inv) << 16) | f2bfbits(acc.x * inv);
        pkt.y = ((unsigned)f2bfbits(acc.w * inv) << 16) | f2bfbits(acc.z * inv);
        *reinterpret_cast<uint2*>(&outb[(size_t)node * D + ch]) = pkt;
    }
}

// ============ BN partial sums over bf16 intermediate ============
__global__ __launch_bounds__(256) void bn_partial_k(
    const __bf16* __restrict__ outb, float* __restrict__ sums,
    float* __restrict__ sumsq, int n) {
    __shared__ float rs[8][128];
    __shared__ float rq[8][128];
    const int c4 = (threadIdx.x & 31) * 4;
    const int rstr = threadIdx.x >> 5;  // 0..7
    float4 s = make_float4(0.f, 0.f, 0.f, 0.f);
    float4 q = make_float4(0.f, 0.f, 0.f, 0.f);
    for (int r = blockIdx.x * 8 + rstr; r < n; r += gridDim.x * 8) {
        const float4 v = ldbf4(&outb[(size_t)r * D + c4]);
        s.x += v.x; s.y += v.y; s.z += v.z; s.w += v.w;
        q.x = fmaf(v.x, v.x, q.x);
        q.y = fmaf(v.y, v.y, q.y);
        q.z = fmaf(v.z, v.z, q.z);
        q.w = fmaf(v.w, v.w, q.w);
    }
    rs[rstr][c4 + 0] = s.x; rs[rstr][c4 + 1] = s.y;
    rs[rstr][c4 + 2] = s.z; rs[rstr][c4 + 3] = s.w;
    rq[rstr][c4 + 0] = q.x; rq[rstr][c4 + 1] = q.y;
    rq[rstr][c4 + 2] = q.z; rq[rstr][c4 + 3] = q.w;
    __syncthreads();
    const int t = threadIdx.x;
    if (t < 128) {
        float a = 0.f;
#pragma unroll
        for (int j = 0; j < 8; ++j) a += rs[j][t];
        atomicAdd(&sums[t], a);
    } else {
        const int c = t - 128;
        float a = 0.f;
#pragma unroll
        for (int j = 0; j < 8; ++j) a += rq[j][c];
        atomicAdd(&sumsq[c], a);
    }
}

// ============ BN finalize+apply: bf16 in, f32 out ============
__global__ __launch_bounds__(256) void bn_apply_k(
    const __bf16* __restrict__ outb, float* __restrict__ out,
    const float* __restrict__ bnsums, const float* __restrict__ gamma,
    const float* __restrict__ beta, int n, int total4) {
    const int i = blockIdx.x * blockDim.x + threadIdx.x;
    if (i >= total4) return;
    const int c4 = (i & 31) * 4;
    const float inv_n = 1.f / (float)n;
    const float4 sm = *reinterpret_cast<const float4*>(&bnsums[c4]);
    const float4 sq = *reinterpret_cast<const float4*>(&bnsums[D + c4]);
    const float4 g = *reinterpret_cast<const float4*>(&gamma[c4]);
    const float4 bt = *reinterpret_cast<const float4*>(&beta[c4]);
    float4 v = ldbf4(&outb[(size_t)i * 4]);
    float mu, var, scale, shift, r;
    mu = sm.x * inv_n; var = fmaxf(sq.x * inv_n - mu * mu, 0.f);
    scale = g.x * rsqrtf(var + 1e-5f); shift = bt.x - mu * scale;
    r = fmaf(v.x, scale, shift); v.x = fmaxf(r, 0.01f * r);
    mu = sm.y * inv_n; var = fmaxf(sq.y * inv_n - mu * mu, 0.f);
    scale = g.y * rsqrtf(var + 1e-5f); shift = bt.y - mu * scale;
    r = fmaf(v.y, scale, shift); v.y = fmaxf(r, 0.01f * r);
    mu = sm.z * inv_n; var = fmaxf(sq.z * inv_n - mu * mu, 0.f);
    scale = g.z * rsqrtf(var + 1e-5f); shift = bt.z - mu * scale;
    r = fmaf(v.z, scale, shift); v.z = fmaxf(r, 0.01f * r);
    mu = sm.w * inv_n; var = fmaxf(sq.w * inv_n - mu * mu, 0.f);
    scale = g.w * rsqrtf(var + 1e-5f); shift = bt.w - mu * scale;
    r = fmaf(v.w, scale, shift); v.w = fmaxf(r, 0.01f * r);
    *reinterpret_cast<float4*>(&out[(size_t)i * 4]) = v;
}

extern "C" void kernel_launch(void* const* d_in, const int* in_sizes, int n_in,
                              void* d_out, int out_size, void* d_ws, size_t ws_size,
                              hipStream_t stream) {
    const float* x     = (const float*)d_in[0];
    const int*   ei    = (const int*)d_in[1];
    const float* ew    = (const float*)d_in[2];
    const float* Wl    = (const float*)d_in[3];
    const float* Wr    = (const float*)d_in[4];
    const float* We    = (const float*)d_in[5];
    const float* att   = (const float*)d_in[6];
    // d_in[7] = bias: cancels exactly inside BatchNorm (mean subtraction)
    const float* gamma = (const float*)d_in[8];
    const float* beta  = (const float*)d_in[9];

    const int n = in_sizes[0] / D;   // 100000 nodes
    const int E = in_sizes[2];       // 800000 edges
    const int* src = ei;
    const int* dst = ei + E;
    const int nblk = (n + 255) / 256;

    char* ws = (char*)d_ws;
    size_t off = 0;
    __bf16* xl = (__bf16*)(ws + off);   off += (size_t)n * D * 2;
    __bf16* xr = (__bf16*)(ws + off);   off += (size_t)n * D * 2;
    __bf16* outb = (__bf16*)(ws + off); off += (size_t)n * D * 2;
    __bf16* Wbf = (__bf16*)(ws + off);  off += (size_t)2 * D * D * 2;
    // zero region (contiguous): bnsums (2*D f) + scanctr (4) + deg (n ints)
    float* bnsums = (float*)(ws + off); off += 2 * D * sizeof(float);
    int* scanctr = (int*)(ws + off);    off += 4 * sizeof(int);
    int* deg = (int*)(ws + off);        off += (size_t)n * sizeof(int);
    int* rowptr = (int*)(ws + off);     off += ((size_t)n + 1) * sizeof(int);
    unsigned char* rank = (unsigned char*)(ws + off); off += (size_t)E;
    off = (off + 15) & ~(size_t)15;
    int2* epay = (int2*)(ws + off);     off += (size_t)E * sizeof(int2);

    float* outacc = (float*)d_out;

    const int zcount = 2 * D + 4 + n;
    const int zblocks = (zcount + 255) / 256;

    // K0: W preswizzle || zero deg/bnsums/scanctr
    wprep_zero_k<<<128 + zblocks, 256, 0, stream>>>(Wl, Wr, Wbf,
                                                    (int*)bnsums, zcount);

    // persistent MFMA GEMM (512 blocks) || deg + rank capture
    const int nTiles = (n + 63) / 64;
    const int gemmGrid = 512;
    const int degBlocks = (E + 255) / 256;
    gemm_deg_k<<<gemmGrid + degBlocks, 256, 0, stream>>>(
        x, Wbf, xl, xr, n, nTiles, gemmGrid, dst, deg, rank, E);

    // single-pass ticket scan
    scan_k<<<nblk, 256, 0, stream>>>(deg, rowptr, scanctr, n);

    // atomic-free XCD-partitioned payload scatter
    fill_k<<<2048, 256, 0, stream>>>(src, dst, ew, rowptr, rank, epay, E, n);

    // one pair of nodes per wave, 4-edge unroll
    const int waves = (n + 1) / 2;
    node_aggr_k<<<(waves + 3) / 4, 256, 0, stream>>>(xl, xr, epay, rowptr,
                                                     deg, We, att, outb, n);

    bn_partial_k<<<512, 256, 0, stream>>>(outb, bnsums, bnsums + D, n);
    bn_apply_k<<<((n * D / 4) + 255) / 256, 256, 0, stream>>>(
        outb, outacc, bnsums, gamma, beta, n, n * D / 4);
}